// Round 4
// baseline (219.165 us; speedup 1.0000x reference)
//
#include <hip/hip_runtime.h>

// PaddedToSegments: batched stream compaction, single fused kernel.
//   inputs: [B=16, T=2048, D=1024] f32
//   mask:   [B, T] bool (int32 per harness convention)
// Outputs flat f32: collected [B,T,D], valid_idx [B,T] (-1 tail), counts [B].
//
// Every block redundantly computes its sample's full mask prefix-scan
// (8 KB mask, L2-resident; wave shfl scan + 4 wave totals in LDS) so there is
// no scan->gather kernel dependency. Block (b, chunk) owns input rows
// [chunk*16, chunk*16+16): valid rows copy to compacted slot excl(t); rows
// t >= count are zero-filled (union over chunks covers the whole tail).

#define BB 16
#define TT 2048
#define DD 1024
#define ROW4 (DD / 4)     // 256 float4 per row
#define RPB 16            // input rows per block
#define CHUNKS (TT / RPB) // 128

typedef float f4 __attribute__((ext_vector_type(4)));

__global__ __launch_bounds__(256) void fused_compact_kernel(
    const f4* __restrict__ in,        // [B*T][256]
    const int* __restrict__ mask,     // [B][T]
    f4* __restrict__ out,             // [B*T][256]
    float* __restrict__ out_vidx,     // [B][T]
    float* __restrict__ out_counts)   // [B]
{
    const int tid   = threadIdx.x;
    const int b     = blockIdx.x >> 7;          // / CHUNKS
    const int chunk = blockIdx.x & (CHUNKS - 1);
    const int t0    = chunk * RPB;

    // ---- full-sample mask scan (every block, redundant, L2-fed) ----
    const int4* m4 = (const int4*)(mask + b * TT);
    int4 a0 = m4[tid * 2];
    int4 a1 = m4[tid * 2 + 1];
    int v[8];
    v[0] = (a0.x != 0); v[1] = (a0.y != 0); v[2] = (a0.z != 0); v[3] = (a0.w != 0);
    v[4] = (a1.x != 0); v[5] = (a1.y != 0); v[6] = (a1.z != 0); v[7] = (a1.w != 0);
    int pre[8];
    int s = 0;
#pragma unroll
    for (int i = 0; i < 8; ++i) { pre[i] = s; s += v[i]; }

    // wave-level inclusive scan of per-thread sums (no barriers)
    int incl = s;
#pragma unroll
    for (int off = 1; off < 64; off <<= 1) {
        int n = __shfl_up(incl, off, 64);
        if ((tid & 63) >= off) incl += n;
    }

    __shared__ int wsum[4];
    __shared__ int l_dst[RPB];
    if ((tid & 63) == 63) wsum[tid >> 6] = incl;
    __syncthreads();
    int woff = 0;
    const int wid = tid >> 6;
#pragma unroll
    for (int w = 0; w < 4; ++w) woff += (w < wid) ? wsum[w] : 0;
    const int total = wsum[0] + wsum[1] + wsum[2] + wsum[3];
    const int excl_base = woff + incl - s;   // global exclusive prefix at t = tid*8

    // ---- populate destination slots for this block's 16 input rows ----
    const int first_tid = t0 >> 3;           // rows t0..t0+15 live in threads first_tid, first_tid+1
    if (tid == first_tid || tid == first_tid + 1) {
        const int base_li = (tid - first_tid) * 8;
#pragma unroll
        for (int i = 0; i < 8; ++i) {
            const int dst = v[i] ? (excl_base + pre[i]) : -1;
            l_dst[base_li + i] = dst;
            if (dst >= 0) out_vidx[b * TT + dst] = (float)(tid * 8 + i);
        }
    }
    if (chunk == 0 && tid == 0) out_counts[b] = (float)total;
    __syncthreads();

    // ---- copy / zero phase: 16 lanes per row, 16 f4 per thread ----
    const int lrow = tid >> 4;    // 0..15
    const int lane = tid & 15;    // 0..15
    const int t    = t0 + lrow;
    const int dst  = l_dst[lrow];
    const size_t inbase = (size_t)b * TT;

    if (dst >= 0) {
        const f4* sp = in + (inbase + (size_t)t) * ROW4 + lane;
        f4* dp = out + (inbase + (size_t)dst) * ROW4 + lane;
        f4 vv[16];
#pragma unroll
        for (int j = 0; j < 16; ++j)
            vv[j] = __builtin_nontemporal_load(sp + j * 16);
#pragma unroll
        for (int j = 0; j < 16; ++j)
            __builtin_nontemporal_store(vv[j], dp + j * 16);
    }
    if (t >= total) {
        f4* dp = out + (inbase + (size_t)t) * ROW4 + lane;
        const f4 z = {0.f, 0.f, 0.f, 0.f};
#pragma unroll
        for (int j = 0; j < 16; ++j)
            __builtin_nontemporal_store(z, dp + j * 16);
        if (lane == 0) out_vidx[b * TT + t] = -1.0f;
    }
}

extern "C" void kernel_launch(void* const* d_in, const int* in_sizes, int n_in,
                              void* d_out, int out_size, void* d_ws, size_t ws_size,
                              hipStream_t stream) {
    const float* inputs = (const float*)d_in[0];
    const int* mask = (const int*)d_in[1];

    float* out = (float*)d_out;
    float* out_collected = out;                       // B*T*D
    float* out_vidx = out + (size_t)BB * TT * DD;     // B*T
    float* out_counts = out_vidx + (size_t)BB * TT;   // B

    fused_compact_kernel<<<BB * CHUNKS, 256, 0, stream>>>(
        (const f4*)inputs, mask, (f4*)out_collected, out_vidx, out_counts);
}